// Round 1
// baseline (1558.550 us; speedup 1.0000x reference)
//
#include <hip/hip_runtime.h>
#include <hip/hip_bf16.h>

#define VOCAB 50000
#define EDIM 256
#define HDIM 256
#define BATCH 64
#define SEQ 2048

// ---------------- kernel 0: transpose W_ih (H x E) -> W_T (E x H) -------------
__global__ void k_transpose(const float* __restrict__ W, float* __restrict__ WT) {
    int idx = blockIdx.x * 256 + threadIdx.x;   // idx = e*256 + i
    int e = idx >> 8;
    int i = idx & 255;
    WT[idx] = W[i * 256 + e];                   // uncoalesced read, one-time 256KB
}

// ---------------- kernel 1: P[v][i] = sum_e emb[v][e] * W_ih[i][e] ------------
// Tile: 32 vocab rows per WG, 256 threads, thread owns output column i = tid.
// emb tile staged in LDS (32KB), read back as float4 broadcasts (1 LDS inst : 4 FMA).
__global__ __launch_bounds__(256) void k_project(const float* __restrict__ emb,
                                                 const float* __restrict__ WT,
                                                 float* __restrict__ P) {
    __shared__ float etile[32 * 256];
    const int v0 = blockIdx.x * 32;
    const int tid = threadIdx.x;

    #pragma unroll 4
    for (int k = 0; k < 32; ++k) {
        int v = v0 + k;
        etile[k * 256 + tid] = (v < VOCAB) ? emb[(size_t)v * 256 + tid] : 0.0f;
    }
    __syncthreads();

    float acc[32];
    #pragma unroll
    for (int k = 0; k < 32; ++k) acc[k] = 0.0f;

    for (int e0 = 0; e0 < 256; e0 += 4) {
        // coalesced, L2-hot after the first wave of WGs
        float w0 = WT[(size_t)(e0 + 0) * 256 + tid];
        float w1 = WT[(size_t)(e0 + 1) * 256 + tid];
        float w2 = WT[(size_t)(e0 + 2) * 256 + tid];
        float w3 = WT[(size_t)(e0 + 3) * 256 + tid];
        #pragma unroll
        for (int k = 0; k < 32; ++k) {
            float4 ev = *(const float4*)&etile[k * 256 + e0];  // broadcast read
            acc[k] = fmaf(ev.x, w0, acc[k]);
            acc[k] = fmaf(ev.y, w1, acc[k]);
            acc[k] = fmaf(ev.z, w2, acc[k]);
            acc[k] = fmaf(ev.w, w3, acc[k]);
        }
    }
    #pragma unroll 4
    for (int k = 0; k < 32; ++k) {
        int v = v0 + k;
        if (v < VOCAB) P[(size_t)v * 256 + tid] = acc[k];
    }
}

// ---------------- kernel 2: the recurrence, one WG (1024 thr) per batch -------
// Thread layout: cg = tid>>7 (8 column groups of 32 cols), s = tid&127,
// thread owns rows {2s, 2s+1} x cols [32cg, 32cg+32) of W_hh in registers.
// Per step: h broadcast-read from LDS (float4), 64 FMAs/thread, partial sums
// (8 col-groups) reduced through LDS by threads 0..255, + prefetched x-proj row,
// fast tanh, h written back. Two barriers per step.
__device__ __forceinline__ float tanh_fast(float x) {
    float ax = fabsf(x);
    float e  = __expf(-2.0f * ax);          // v_exp_f32 based, ~2 ulp
    float r  = (1.0f - e) / (1.0f + e);     // stable, r in [0,1)
    return copysignf(r, x);
}

__global__ __launch_bounds__(1024, 4) void k_rnn(const int* __restrict__ tokens,
                                                 const int* __restrict__ lengths,
                                                 const float* __restrict__ P,
                                                 const float* __restrict__ Whh,
                                                 const float* __restrict__ Wcls,
                                                 const float* __restrict__ bcls,
                                                 float* __restrict__ out) {
    __shared__ float h_lds[256];
    __shared__ float partials[8 * 256];
    __shared__ int   tok_lds[SEQ];

    const int b   = blockIdx.x;
    const int tid = threadIdx.x;
    const int len = lengths[b];             // uniform, in [1, SEQ]

    // stage this batch's tokens (coalesced)
    tok_lds[tid]        = tokens[b * SEQ + tid];
    tok_lds[tid + 1024] = tokens[b * SEQ + tid + 1024];
    if (tid < 256) h_lds[tid] = 0.0f;

    // W_hh -> registers: rows 2s, 2s+1, cols 32cg..32cg+31
    const int cg = tid >> 7;
    const int s  = tid & 127;
    const int r0 = 2 * s;
    float w0[32], w1[32];
    {
        const float4* Wr0 = (const float4*)(Whh + (size_t)r0 * 256 + cg * 32);
        const float4* Wr1 = (const float4*)(Whh + (size_t)(r0 + 1) * 256 + cg * 32);
        #pragma unroll
        for (int m = 0; m < 8; ++m) {
            float4 a = Wr0[m], c = Wr1[m];
            w0[4*m+0] = a.x; w0[4*m+1] = a.y; w0[4*m+2] = a.z; w0[4*m+3] = a.w;
            w1[4*m+0] = c.x; w1[4*m+1] = c.y; w1[4*m+2] = c.z; w1[4*m+3] = c.w;
        }
    }
    __syncthreads();

    float xp_cur = 0.0f, xp_next = 0.0f;
    if (tid < 256) {
        int t0 = tok_lds[0];
        xp_cur = P[(size_t)t0 * 256 + tid];  // x-proj row for step 0
    }

    for (int t = 0; t < len; ++t) {
        // prefetch next step's x-proj row (in flight across the FMA phase)
        if (tid < 256 && t + 1 < len) {
            int tn = tok_lds[t + 1];
            xp_next = P[(size_t)tn * 256 + tid];
        }

        // ---- FMA phase: all 16 waves; h reads are wave-uniform broadcasts ----
        float a0 = 0.f, a1 = 0.f, c0 = 0.f, c1 = 0.f;  // 4 chains for ILP
        const float4* hv = (const float4*)(h_lds + cg * 32);
        #pragma unroll
        for (int m = 0; m < 8; m += 2) {
            float4 h0 = hv[m];
            a0 = fmaf(w0[4*m+0], h0.x, a0);  a1 = fmaf(w1[4*m+0], h0.x, a1);
            a0 = fmaf(w0[4*m+1], h0.y, a0);  a1 = fmaf(w1[4*m+1], h0.y, a1);
            a0 = fmaf(w0[4*m+2], h0.z, a0);  a1 = fmaf(w1[4*m+2], h0.z, a1);
            a0 = fmaf(w0[4*m+3], h0.w, a0);  a1 = fmaf(w1[4*m+3], h0.w, a1);
            float4 h1 = hv[m + 1];
            c0 = fmaf(w0[4*m+4], h1.x, c0);  c1 = fmaf(w1[4*m+4], h1.x, c1);
            c0 = fmaf(w0[4*m+5], h1.y, c0);  c1 = fmaf(w1[4*m+5], h1.y, c1);
            c0 = fmaf(w0[4*m+6], h1.z, c0);  c1 = fmaf(w1[4*m+6], h1.z, c1);
            c0 = fmaf(w0[4*m+7], h1.w, c0);  c1 = fmaf(w1[4*m+7], h1.w, c1);
        }
        float acc0 = a0 + c0, acc1 = a1 + c1;
        *(float2*)&partials[cg * 256 + r0] = make_float2(acc0, acc1);  // 8B, conflict-light
        __syncthreads();

        // ---- reduce + tanh phase: threads 0..255 (4 waves) ----
        if (tid < 256) {
            float p = 0.f;
            #pragma unroll
            for (int g = 0; g < 8; ++g) p += partials[g * 256 + tid];  // 2-way free
            float hn = tanh_fast(xp_cur + p);
            h_lds[tid] = hn;
            xp_cur = xp_next;
        }
        __syncthreads();
    }

    // ---- classifier head: logits[c] = dot(W_cls[c], h_last) + b_cls[c] ----
    if (tid < 128) {
        int c = tid >> 6, l = tid & 63;
        float sacc = 0.f;
        #pragma unroll
        for (int q = 0; q < 4; ++q)
            sacc += Wcls[c * 256 + q * 64 + l] * h_lds[q * 64 + l];
        #pragma unroll
        for (int off = 32; off > 0; off >>= 1)
            sacc += __shfl_down(sacc, off, 64);
        if (l == 0) out[b * 2 + c] = sacc + bcls[c];
    }
}

// ------------------------------- launcher ------------------------------------
extern "C" void kernel_launch(void* const* d_in, const int* in_sizes, int n_in,
                              void* d_out, int out_size, void* d_ws, size_t ws_size,
                              hipStream_t stream) {
    const int*   reviews = (const int*)d_in[0];
    const int*   lengths = (const int*)d_in[1];
    const float* emb     = (const float*)d_in[2];
    const float* W_ih    = (const float*)d_in[3];
    const float* W_hh    = (const float*)d_in[4];
    const float* W_cls   = (const float*)d_in[5];
    const float* b_cls   = (const float*)d_in[6];
    float* out = (float*)d_out;

    // workspace layout: [W_T : 256KB][P : 50000*256*4 = 51.2MB]
    float* WT = (float*)d_ws;
    float* P  = WT + 256 * 256;

    k_transpose<<<256, 256, 0, stream>>>(W_ih, WT);
    k_project<<<(VOCAB + 31) / 32, 256, 0, stream>>>(emb, WT, P);
    k_rnn<<<BATCH, 1024, 0, stream>>>(reviews, lengths, P, W_hh, W_cls, b_cls, out);
}

// Round 4
// 1517.589 us; speedup vs baseline: 1.0270x; 1.0270x over previous
//
#include <hip/hip_runtime.h>
#include <hip/hip_bf16.h>

#define VOCAB 50000
#define EDIM 256
#define HDIM 256
#define BATCH 64
#define SEQ 2048

// ---------------- kernel 0: transpose W_ih (H x E) -> W_T (E x H) -------------
__global__ void k_transpose(const float* __restrict__ W, float* __restrict__ WT) {
    int idx = blockIdx.x * 256 + threadIdx.x;   // idx = e*256 + i
    int e = idx >> 8;
    int i = idx & 255;
    WT[idx] = W[i * 256 + e];                   // uncoalesced read, one-time 256KB
}

// ---------------- kernel 1: P[v][i] = sum_e emb[v][e] * W_ih[i][e] ------------
__global__ __launch_bounds__(256) void k_project(const float* __restrict__ emb,
                                                 const float* __restrict__ WT,
                                                 float* __restrict__ P) {
    __shared__ float etile[32 * 256];
    const int v0 = blockIdx.x * 32;
    const int tid = threadIdx.x;

    #pragma unroll 4
    for (int k = 0; k < 32; ++k) {
        int v = v0 + k;
        etile[k * 256 + tid] = (v < VOCAB) ? emb[(size_t)v * 256 + tid] : 0.0f;
    }
    __syncthreads();

    float acc[32];
    #pragma unroll
    for (int k = 0; k < 32; ++k) acc[k] = 0.0f;

    for (int e0 = 0; e0 < 256; e0 += 4) {
        float w0 = WT[(size_t)(e0 + 0) * 256 + tid];
        float w1 = WT[(size_t)(e0 + 1) * 256 + tid];
        float w2 = WT[(size_t)(e0 + 2) * 256 + tid];
        float w3 = WT[(size_t)(e0 + 3) * 256 + tid];
        #pragma unroll
        for (int k = 0; k < 32; ++k) {
            float4 ev = *(const float4*)&etile[k * 256 + e0];
            acc[k] = fmaf(ev.x, w0, acc[k]);
            acc[k] = fmaf(ev.y, w1, acc[k]);
            acc[k] = fmaf(ev.z, w2, acc[k]);
            acc[k] = fmaf(ev.w, w3, acc[k]);
        }
    }
    #pragma unroll 4
    for (int k = 0; k < 32; ++k) {
        int v = v0 + k;
        if (v < VOCAB) P[(size_t)v * 256 + tid] = acc[k];
    }
}

// ---------------- kernel 2: recurrence -----------------------------------------
// T=512. Thread (rg = tid&63, cg = tid>>6) owns rows {4rg+j, j=0..3} x cols
// [32cg, 32cg+32). Weights: 128 VGPRs/thread (static-indexed float4[4][8]).
// h-read: wave-uniform (cg is per-wave) -> 8 ds_read_b128 broadcasts per wave.
// Partial write: one float4 per thread at part[cg][4rg] — stride-16B, bank-balanced.
// Reduce: 256 threads, 8 conflict-free ds_read_b32 each + tanh + h write.
__device__ __forceinline__ float tanh_fast(float x) {
    float ax = fabsf(x);
    float e  = __expf(-2.0f * ax);
    float r  = (1.0f - e) / (1.0f + e);
    return copysignf(r, x);
}

__global__ __launch_bounds__(512, 2) void k_rnn(const int* __restrict__ tokens,
                                                const int* __restrict__ lengths,
                                                const float* __restrict__ P,
                                                const float* __restrict__ Whh,
                                                const float* __restrict__ Wcls,
                                                const float* __restrict__ bcls,
                                                float* __restrict__ out) {
    __shared__ float h_lds[256];
    __shared__ float part[8][256];
    __shared__ int   tok_lds[SEQ];

    const int b   = blockIdx.x;
    const int tid = threadIdx.x;
    const int len = lengths[b];

    #pragma unroll
    for (int k = 0; k < 4; ++k)
        tok_lds[tid + k * 512] = tokens[b * SEQ + tid + k * 512];
    if (tid < 256) h_lds[tid] = 0.0f;

    const int rg = tid & 63;     // lane within wave
    const int cg = tid >> 6;     // wave index = column group (wave-uniform)

    // weights: rows 4rg+j, cols cg*32..cg*32+31  -> 128 floats in VGPRs
    float4 w[4][8];
    #pragma unroll
    for (int j = 0; j < 4; ++j) {
        const float4* src = (const float4*)(Whh + (size_t)(4 * rg + j) * 256 + cg * 32);
        #pragma unroll
        for (int m = 0; m < 8; ++m) w[j][m] = src[m];
    }
    __syncthreads();

    float xp_cur = 0.0f, xp_next = 0.0f;
    if (tid < 256) xp_cur = P[(size_t)tok_lds[0] * 256 + tid];

    for (int t = 0; t < len; ++t) {
        if (tid < 256 && t + 1 < len) {
            int tn = tok_lds[t + 1];
            xp_next = P[(size_t)tn * 256 + tid];   // in flight across FMA phase
        }

        // ---- FMA phase: h broadcast (wave-uniform addr), 128 FMAs/thread ----
        const float4* hv = (const float4*)(h_lds + cg * 32);
        float a0 = 0.f, a1 = 0.f, a2 = 0.f, a3 = 0.f;
        #pragma unroll
        for (int m = 0; m < 8; ++m) {
            float4 h4 = hv[m];
            a0 = fmaf(w[0][m].x, h4.x, a0); a0 = fmaf(w[0][m].y, h4.y, a0);
            a0 = fmaf(w[0][m].z, h4.z, a0); a0 = fmaf(w[0][m].w, h4.w, a0);
            a1 = fmaf(w[1][m].x, h4.x, a1); a1 = fmaf(w[1][m].y, h4.y, a1);
            a1 = fmaf(w[1][m].z, h4.z, a1); a1 = fmaf(w[1][m].w, h4.w, a1);
            a2 = fmaf(w[2][m].x, h4.x, a2); a2 = fmaf(w[2][m].y, h4.y, a2);
            a2 = fmaf(w[2][m].z, h4.z, a2); a2 = fmaf(w[2][m].w, h4.w, a2);
            a3 = fmaf(w[3][m].x, h4.x, a3); a3 = fmaf(w[3][m].y, h4.y, a3);
            a3 = fmaf(w[3][m].z, h4.z, a3); a3 = fmaf(w[3][m].w, h4.w, a3);
        }
        // rows 4rg..4rg+3 contiguous -> one b128, stride 16B across lanes (bank-balanced)
        *(float4*)&part[cg][4 * rg] = make_float4(a0, a1, a2, a3);
        __syncthreads();

        // ---- reduce + tanh: 256 threads, conflict-free b32 reads ----
        if (tid < 256) {
            float s0 = part[0][tid] + part[1][tid];
            float s1 = part[2][tid] + part[3][tid];
            float s2 = part[4][tid] + part[5][tid];
            float s3 = part[6][tid] + part[7][tid];
            float hn = tanh_fast(xp_cur + ((s0 + s1) + (s2 + s3)));
            h_lds[tid] = hn;
            xp_cur = xp_next;
        }
        __syncthreads();
    }

    // ---- classifier head ----
    if (tid < 128) {
        int c = tid >> 6, l = tid & 63;
        float sacc = 0.f;
        #pragma unroll
        for (int q = 0; q < 4; ++q)
            sacc += Wcls[c * 256 + q * 64 + l] * h_lds[q * 64 + l];
        #pragma unroll
        for (int off = 32; off > 0; off >>= 1)
            sacc += __shfl_down(sacc, off, 64);
        if (l == 0) out[b * 2 + c] = sacc + bcls[c];
    }
}

// ------------------------------- launcher ------------------------------------
extern "C" void kernel_launch(void* const* d_in, const int* in_sizes, int n_in,
                              void* d_out, int out_size, void* d_ws, size_t ws_size,
                              hipStream_t stream) {
    const int*   reviews = (const int*)d_in[0];
    const int*   lengths = (const int*)d_in[1];
    const float* emb     = (const float*)d_in[2];
    const float* W_ih    = (const float*)d_in[3];
    const float* W_hh    = (const float*)d_in[4];
    const float* W_cls   = (const float*)d_in[5];
    const float* b_cls   = (const float*)d_in[6];
    float* out = (float*)d_out;

    float* WT = (float*)d_ws;
    float* P  = WT + 256 * 256;

    k_transpose<<<256, 256, 0, stream>>>(W_ih, WT);
    k_project<<<(VOCAB + 31) / 32, 256, 0, stream>>>(emb, WT, P);
    k_rnn<<<BATCH, 512, 0, stream>>>(reviews, lengths, P, W_hh, W_cls, b_cls, out);
}